// Round 10
// baseline (87.302 us; speedup 1.0000x reference)
//
#include <hip/hip_runtime.h>
#include <hip/hip_bf16.h>

#define CC 256
#define HH 200
#define WW 200
#define PLANE (HH * WW)       // 40000
#define OUT_H 7
#define OUT_W 7
#define NSP   (OUT_H * OUT_W) // 49
#define BMAX  1024

// ---------- Pass A: NCHW fp32 -> NHWC bf16 transpose; block (0,0,0) also ----------
// ---------- Morton-sorts the ROIs into perm[] (hidden under the transpose) ----------
__global__ __launch_bounds__(256) void nchw2nhwc_bf16_sort(
    const float* __restrict__ in, __hip_bfloat16* __restrict__ out,
    const float* __restrict__ rois, int B, unsigned short* __restrict__ perm)
{
    __shared__ float tile[64][65];     // +1 pad: conflict-free both phases
    __shared__ unsigned skey[BMAX];    // sort scratch (block 0 only)

    int n  = blockIdx.z;
    int c0 = blockIdx.y * 64;
    int p0 = blockIdx.x * 64;
    int tx = threadIdx.x & 63;
    int ty = threadIdx.x >> 6;         // 0..3

    const float* src = in + ((size_t)n * CC + c0) * PLANE + p0;
    #pragma unroll
    for (int i = 0; i < 16; ++i) {
        int c = i * 4 + ty;
        tile[c][tx] = src[(size_t)c * PLANE + tx];   // lanes contiguous along p
    }
    __syncthreads();
    __hip_bfloat16* dst = out + ((size_t)n * PLANE + p0) * CC + c0;
    #pragma unroll
    for (int i = 0; i < 16; ++i) {
        int p = i * 4 + ty;
        dst[(size_t)p * CC + tx] = __float2bfloat16(tile[tx][p]);  // 128 B/wave-store
    }

    if (blockIdx.x == 0 && blockIdx.y == 0 && blockIdx.z == 0) {
        int t = threadIdx.x;
        for (int i = t; i < BMAX; i += 256) {
            unsigned k = 0xFFFFFFFFu;
            if (i < B) {
                const float* r = rois + i * 5;
                unsigned bi = (unsigned)(int)r[0];
                float cx = (r[1] + r[3]) * 0.125f;   // center * SPATIAL_SCALE
                float cy = (r[2] + r[4]) * 0.125f;
                unsigned ix = (unsigned)fminf(fmaxf(cx, 0.f), 255.f);
                unsigned iy = (unsigned)fminf(fmaxf(cy, 0.f), 255.f);
                unsigned m = 0;
                #pragma unroll
                for (int bp = 0; bp < 8; ++bp) {
                    m |= ((ix >> bp) & 1u) << (2 * bp);
                    m |= ((iy >> bp) & 1u) << (2 * bp + 1);
                }
                k = (bi << 26) | (m << 10) | (unsigned)i;
            }
            skey[i] = k;
        }
        __syncthreads();
        for (int size = 2; size <= BMAX; size <<= 1) {
            for (int stride = size >> 1; stride > 0; stride >>= 1) {
                for (int i = t; i < BMAX; i += 256) {
                    int p = i ^ stride;
                    if (p > i) {
                        bool up = ((i & size) == 0);
                        unsigned a = skey[i], b2 = skey[p];
                        if ((a > b2) == up) { skey[i] = b2; skey[p] = a; }
                    }
                }
                __syncthreads();
            }
        }
        for (int i = t; i < BMAX; i += 256) perm[i] = (unsigned short)(skey[i] & 1023u);
    }
}

// ---------- Pass B: 2 blocks per ROI (128 ch each); PAIRED-CORNER wave loads ----------
// One uint2 load instr covers BOTH x-corners (lanes 0-31 -> pixel x0 half,
// lanes 32-63 -> pixel x1 half): 512 B in flight per vmcnt slot, half the
// load-instruction count of R9. __shfl_xor(32) swaps corners; lanes<32 own
// 4 channels each (upper half-wave computes redundantly - VALU is idle anyway).
__global__ __launch_bounds__(256) void roialign_nhwc_pair(
    const __hip_bfloat16* __restrict__ nhwc,    // (N, H, W, C) bf16
    const float* __restrict__ rois,             // (B, 5)
    const unsigned short* __restrict__ perm,    // Morton-sorted roi ids
    float* __restrict__ out)                    // (B, C, 7, 7) fp32
{
    __shared__ float obuf[128 * NSP];  // 25088 B
    int nblk = gridDim.x;              // B*2
    int bid  = blockIdx.x;
    int pos;
    if ((nblk & 7) == 0) { int cpx = nblk >> 3; pos = (bid & 7) * cpx + (bid >> 3); }
    else                 { pos = bid; }
    int slot = pos >> 1;
    int cg   = pos & 1;                // 128-channel half
    int b    = (int)perm[slot];

    int t   = threadIdx.x;
    int q   = t & 63;
    int wv  = t >> 6;
    int ql  = q & 31;
    bool hi = (q >= 32);

    const float* r = rois + b * 5;
    int   bi  = (int)r[0];
    float rx1 = r[1] * 0.25f, ry1 = r[2] * 0.25f;
    float rx2 = r[3] * 0.25f, ry2 = r[4] * 0.25f;
    float bin_w = fmaxf(rx2 - rx1, 1.0f) * (1.0f / OUT_W);
    float bin_h = fmaxf(ry2 - ry1, 1.0f) * (1.0f / OUT_H);

    // tb points at this ROI's image, this block's channel half (cg*256 B).
    const char* tb = (const char*)nhwc + (size_t)bi * PLANE * (CC * 2) + cg * 256;
    int laneoff = ql * 8 + (hi ? 512 : 0);   // hi lanes read pixel x0+1's half

    int s0 = wv * 13;                  // contiguous chunk; wave 3 clamps (repeats benign)
    #pragma unroll
    for (int k = 0; k < 13; ++k) {
        int s  = min(s0 + k, NSP - 1);
        int pw = s % 7, ph = s / 7;
        float acc0 = 0.f, acc1 = 0.f, acc2 = 0.f, acc3 = 0.f;
        #pragma unroll
        for (int iy = 0; iy < 2; ++iy) {
            float yy = ry1 + ((float)ph + ((float)iy + 0.5f) * 0.5f) * bin_h;
            float py = fminf(fmaxf(yy - 0.5f, 0.0f), (float)(HH - 1));
            int   y0 = min((int)py, HH - 2);
            float fy = py - (float)y0;
            #pragma unroll
            for (int ix = 0; ix < 2; ++ix) {
                float xx = rx1 + ((float)pw + ((float)ix + 0.5f) * 0.5f) * bin_w;
                float px = fminf(fmaxf(xx - 0.5f, 0.0f), (float)(WW - 1));
                int   x0 = min((int)px, WW - 2);
                float fx = px - (float)x0;

                const char* pbase = tb + (size_t)(y0 * WW + x0) * 512;
                uint2 A = *(const uint2*)(pbase + laneoff);             // row y0, own corner
                uint2 Bv = *(const uint2*)(pbase + WW * 512 + laneoff); // row y1, own corner
                uint2 Ap, Bp;
                Ap.x = __shfl_xor(A.x, 32);  Ap.y = __shfl_xor(A.y, 32);
                Bp.x = __shfl_xor(Bv.x, 32); Bp.y = __shfl_xor(Bv.y, 32);

                uint2 v00 = hi ? Ap : A;    // (y0, x0)
                uint2 v01 = hi ? A  : Ap;   // (y0, x1)
                uint2 v10 = hi ? Bp : Bv;   // (y1, x0)
                uint2 v11 = hi ? Bv : Bp;   // (y1, x1)

                float w00 = (1.f - fy) * (1.f - fx);
                float w01 = (1.f - fy) * fx;
                float w10 = fy * (1.f - fx);
                float w11 = fy * fx;

                union { unsigned u; float f; } c;
                // channel r=0: low bf16 of .x
                c.u = v00.x << 16;         float p0v = c.f * w00;
                c.u = v01.x << 16;         p0v += c.f * w01;
                c.u = v10.x << 16;         p0v += c.f * w10;
                c.u = v11.x << 16;         p0v += c.f * w11;
                acc0 += p0v;
                // r=1: high bf16 of .x
                c.u = v00.x & 0xFFFF0000u; float p1v = c.f * w00;
                c.u = v01.x & 0xFFFF0000u; p1v += c.f * w01;
                c.u = v10.x & 0xFFFF0000u; p1v += c.f * w10;
                c.u = v11.x & 0xFFFF0000u; p1v += c.f * w11;
                acc1 += p1v;
                // r=2: low bf16 of .y
                c.u = v00.y << 16;         float p2v = c.f * w00;
                c.u = v01.y << 16;         p2v += c.f * w01;
                c.u = v10.y << 16;         p2v += c.f * w10;
                c.u = v11.y << 16;         p2v += c.f * w11;
                acc2 += p2v;
                // r=3: high bf16 of .y
                c.u = v00.y & 0xFFFF0000u; float p3v = c.f * w00;
                c.u = v01.y & 0xFFFF0000u; p3v += c.f * w01;
                c.u = v10.y & 0xFFFF0000u; p3v += c.f * w10;
                c.u = v11.y & 0xFFFF0000u; p3v += c.f * w11;
                acc3 += p3v;
            }
        }
        if (!hi) {                      // lanes 0-31 own channels 4*ql .. 4*ql+3
            obuf[(4 * ql + 0) * NSP + s] = acc0 * 0.25f;
            obuf[(4 * ql + 1) * NSP + s] = acc1 * 0.25f;
            obuf[(4 * ql + 2) * NSP + s] = acc2 * 0.25f;
            obuf[(4 * ql + 3) * NSP + s] = acc3 * 0.25f;
        }
    }
    __syncthreads();

    // Contiguous 6272-float run (not /256 -> runtime-bounded); NT stores.
    float* ob = out + (size_t)b * (CC * NSP) + (size_t)cg * (128 * NSP);
    for (int k = t; k < 128 * NSP; k += 256)
        __builtin_nontemporal_store(obuf[k], &ob[k]);
}

// ---------- Fallback (ws too small / B too big): thread-per-output ----------
__global__ __launch_bounds__(256) void roialign_fallback(
    const float* __restrict__ feat, const float* __restrict__ rois,
    float* __restrict__ out, int total)
{
    int idx = blockIdx.x * blockDim.x + threadIdx.x;
    if (idx >= total) return;
    int pw = idx % OUT_W;
    int ph = (idx / OUT_W) % OUT_H;
    int c  = (idx / NSP) % CC;
    int b  = idx / (NSP * CC);

    const float* r = rois + b * 5;
    int   bi  = (int)r[0];
    float rx1 = r[1] * 0.25f, ry1 = r[2] * 0.25f;
    float rx2 = r[3] * 0.25f, ry2 = r[4] * 0.25f;
    float bin_w = fmaxf(rx2 - rx1, 1.0f) * (1.0f / OUT_W);
    float bin_h = fmaxf(ry2 - ry1, 1.0f) * (1.0f / OUT_H);

    const float* fptr = feat + ((size_t)bi * CC + c) * PLANE;
    float acc = 0.0f;
    #pragma unroll
    for (int iy = 0; iy < 2; ++iy) {
        float yy = ry1 + ((float)ph + ((float)iy + 0.5f) * 0.5f) * bin_h;
        float py = fminf(fmaxf(yy - 0.5f, 0.0f), (float)(HH - 1));
        int   y0 = min((int)py, HH - 2);
        float fy = py - (float)y0;
        #pragma unroll
        for (int ix = 0; ix < 2; ++ix) {
            float xx = rx1 + ((float)pw + ((float)ix + 0.5f) * 0.5f) * bin_w;
            float px = fminf(fmaxf(xx - 0.5f, 0.0f), (float)(WW - 1));
            int   x0 = min((int)px, WW - 2);
            float fx = px - (float)x0;
            const float* p = fptr + y0 * WW + x0;
            acc += p[0]      * (1.f - fy) * (1.f - fx)
                 + p[1]      * (1.f - fy) * fx
                 + p[WW]     * fy * (1.f - fx)
                 + p[WW + 1] * fy * fx;
        }
    }
    out[idx] = acc * 0.25f;
}

extern "C" void kernel_launch(void* const* d_in, const int* in_sizes, int n_in,
                              void* d_out, int out_size, void* d_ws, size_t ws_size,
                              hipStream_t stream) {
    const float* feat = (const float*)d_in[0];
    const float* rois = (const float*)d_in[1];
    float* out = (float*)d_out;

    int N = in_sizes[0] / (CC * PLANE);   // 4
    int B = in_sizes[1] / 5;              // 1024

    size_t nhwc_bytes = (size_t)N * PLANE * CC * sizeof(__hip_bfloat16);  // 81,920,000
    size_t need = nhwc_bytes + BMAX * sizeof(unsigned short);

    if (ws_size >= need && B <= BMAX) {
        __hip_bfloat16* nhwc = (__hip_bfloat16*)d_ws;
        unsigned short* perm = (unsigned short*)((char*)d_ws + nhwc_bytes);
        nchw2nhwc_bf16_sort<<<dim3(PLANE / 64, CC / 64, N), 256, 0, stream>>>(
            feat, nhwc, rois, B, perm);
        roialign_nhwc_pair<<<dim3(B * 2), 256, 0, stream>>>(nhwc, rois, perm, out);
    } else {
        int total = out_size;
        roialign_fallback<<<(total + 255) / 256, 256, 0, stream>>>(feat, rois, out, total);
    }
}